// Round 1
// baseline (4693.623 us; speedup 1.0000x reference)
//
#include <hip/hip_runtime.h>
#include <math.h>

#define NTREES 512
#define DEPTH  10
#define NPT    1023
#define NTOT   (NTREES * NPT)   // 523776
#define H      64
#define SEGS   16

__device__ __forceinline__ float sigm(float x) { return 1.0f / (1.0f + expf(-x)); }

// One thread per node at this tree level. lvl = 9 (leaves) .. 0 (root).
// Grid is sized exactly: NTREES<<lvl threads, always a multiple of 256.
template<bool LEAF>
__global__ __launch_bounds__(256, 1)
void level_kernel(const float* __restrict__ feat,
                  const float* __restrict__ w_iou, const float* __restrict__ b_iou,
                  const float* __restrict__ u_iou,
                  const float* __restrict__ w_f, const float* __restrict__ b_f,
                  const float* __restrict__ u_f,
                  float* __restrict__ h, float* __restrict__ c,
                  int lvl)
{
    const int m = 1 << lvl;
    int tid = blockIdx.x * 256 + threadIdx.x;
    int tree = tid >> lvl;
    int i    = tid & (m - 1);
    int local = (m - 1) + i;               // heap index within tree
    long node = (long)tree * NPT + local;

    // per-lane feature row in registers (indices all compile-time)
    float ft[H];
    {
        const float4* p = reinterpret_cast<const float4*>(feat + node * H);
        #pragma unroll
        for (int q = 0; q < H / 4; ++q) {
            float4 v = p[q];
            ft[4*q+0] = v.x; ft[4*q+1] = v.y; ft[4*q+2] = v.z; ft[4*q+3] = v.w;
        }
    }

    float h0[H], h1[H];
    long c0 = 0, c1 = 0;
    if (!LEAF) {
        c0 = (long)tree * NPT + 2 * local + 1;
        c1 = c0 + 1;
        const float4* p0 = reinterpret_cast<const float4*>(h + c0 * H);
        const float4* p1 = reinterpret_cast<const float4*>(h + c1 * H);
        #pragma unroll
        for (int q = 0; q < H / 4; ++q) {
            float4 v = p0[q];
            h0[4*q+0]=v.x; h0[4*q+1]=v.y; h0[4*q+2]=v.z; h0[4*q+3]=v.w;
            float4 w = p1[q];
            h1[4*q+0]=w.x; h1[4*q+1]=w.y; h1[4*q+2]=w.z; h1[4*q+3]=w.w;
        }
    }

    float* hrow = h + node * H;
    float* crow = c + node * H;

    for (int j = 0; j < H; ++j) {          // j is wave-uniform -> weights via s_load
        float ai = b_iou[j];
        float ao = b_iou[H + j];
        float au = b_iou[2 * H + j];
        const float* wi = w_iou + j * H;
        const float* wo = w_iou + (H + j) * H;
        const float* wu = w_iou + (2 * H + j) * H;
        if (LEAF) {
            #pragma unroll
            for (int k = 0; k < H; ++k) {
                float f = ft[k];
                ai = fmaf(wi[k], f, ai);
                ao = fmaf(wo[k], f, ao);
                au = fmaf(wu[k], f, au);
            }
            float ig = sigm(ai), og = sigm(ao), ug = tanhf(au);
            float cval = ig * ug;
            crow[j] = cval;
            hrow[j] = og * tanhf(cval);
        } else {
            const float* ui = u_iou + j * H;
            const float* uo = u_iou + (H + j) * H;
            const float* uu = u_iou + (2 * H + j) * H;
            const float* wf = w_f + j * H;
            const float* uf = u_f + j * H;
            float afx = b_f[j];
            float af0 = 0.0f, af1 = 0.0f;
            #pragma unroll
            for (int k = 0; k < H; ++k) {
                float f = ft[k];
                float a = h0[k], b = h1[k];
                ai = fmaf(wi[k], f, ai);
                ao = fmaf(wo[k], f, ao);
                au = fmaf(wu[k], f, au);
                afx = fmaf(wf[k], f, afx);
                float uiv = ui[k];
                ai = fmaf(uiv, a, ai); ai = fmaf(uiv, b, ai);
                float uov = uo[k];
                ao = fmaf(uov, a, ao); ao = fmaf(uov, b, ao);
                float uuv = uu[k];
                au = fmaf(uuv, a, au); au = fmaf(uuv, b, au);
                float ufv = uf[k];
                af0 = fmaf(ufv, a, af0);
                af1 = fmaf(ufv, b, af1);
            }
            float ig = sigm(ai), og = sigm(ao), ug = tanhf(au);
            float f0 = sigm(afx + af0), f1 = sigm(afx + af1);
            float csum = f0 * c[c0 * H + j] + f1 * c[c1 * H + j];
            float cval = fmaf(ig, ug, csum);
            crow[j] = cval;
            hrow[j] = og * tanhf(cval);
        }
    }
}

// Phase A of mean-pool: deterministic segmented partial sums (no atomics).
__global__ void pool_partial(const float* __restrict__ h, float* __restrict__ part)
{
    int tid = blockIdx.x * 256 + threadIdx.x;   // SEGS*NTREES*H = 524288 threads
    int j    = tid & (H - 1);
    int tree = (tid >> 6) & (NTREES - 1);
    int seg  = tid >> 15;
    int i0 = seg * 64;
    int i1 = i0 + 64; if (i1 > NPT) i1 = NPT;
    float s = 0.0f;
    for (int i = i0; i < i1; ++i)
        s += h[((long)tree * NPT + i) * H + j];
    part[(long)seg * (NTREES * H) + tree * H + j] = s;
}

// Phase B: finish mean, apply relu.
__global__ void pool_final(const float* __restrict__ part, float* __restrict__ x)
{
    int tid = blockIdx.x * 256 + threadIdx.x;   // NTREES*H = 32768 threads
    float s = 0.0f;
    #pragma unroll
    for (int seg = 0; seg < SEGS; ++seg)
        s += part[seg * (NTREES * H) + tid];
    s *= (1.0f / 1023.0f);
    x[tid] = fmaxf(s, 0.0f);
}

// One wave per tree: x(relu'd) -> relu(lin0) -> relu(lin1) -> out_w dot.
__global__ void mlp_kernel(const float* __restrict__ x,
                           const float* __restrict__ l0w, const float* __restrict__ l0b,
                           const float* __restrict__ l1w, const float* __restrict__ l1b,
                           const float* __restrict__ ow,  const float* __restrict__ ob,
                           float* __restrict__ out)
{
    int tree = blockIdx.x;
    int j = threadIdx.x;
    __shared__ float xb[H];
    __shared__ float yb[H];
    xb[j] = x[tree * H + j];
    __syncthreads();
    float acc = l0b[j];
    #pragma unroll
    for (int k = 0; k < H; ++k) acc = fmaf(l0w[j * H + k], xb[k], acc);
    acc = fmaxf(acc, 0.0f);
    yb[j] = acc;
    __syncthreads();
    float acc2 = l1b[j];
    #pragma unroll
    for (int k = 0; k < H; ++k) acc2 = fmaf(l1w[j * H + k], yb[k], acc2);
    acc2 = fmaxf(acc2, 0.0f);
    float t = ow[j] * acc2;
    #pragma unroll
    for (int off = 32; off > 0; off >>= 1) t += __shfl_down(t, off);
    if (j == 0) out[tree] = t + ob[0];
}

extern "C" void kernel_launch(void* const* d_in, const int* in_sizes, int n_in,
                              void* d_out, int out_size, void* d_ws, size_t ws_size,
                              hipStream_t stream)
{
    const float* feat  = (const float*)d_in[0];
    // d_in[1..3]: node_order / adjacency_list / edge_order -- structure is
    // analytic (complete heap-indexed binary trees), not needed.
    const float* w_iou = (const float*)d_in[4];
    const float* b_iou = (const float*)d_in[5];
    const float* u_iou = (const float*)d_in[6];
    const float* w_f   = (const float*)d_in[7];
    const float* b_f   = (const float*)d_in[8];
    const float* u_f   = (const float*)d_in[9];
    const float* l0w   = (const float*)d_in[10];
    const float* l0b   = (const float*)d_in[11];
    const float* l1w   = (const float*)d_in[12];
    const float* l1b   = (const float*)d_in[13];
    const float* ow    = (const float*)d_in[14];
    const float* ob    = (const float*)d_in[15];
    float* out = (float*)d_out;

    // workspace layout (fp32): h[NTOT*H] | c[NTOT*H] | part[SEGS*NTREES*H] | x[NTREES*H]
    float* h    = (float*)d_ws;
    float* c    = h + (size_t)NTOT * H;
    float* part = c + (size_t)NTOT * H;
    float* x    = part + (size_t)SEGS * NTREES * H;

    for (int lvl = DEPTH - 1; lvl >= 0; --lvl) {
        int M = NTREES << lvl;
        int blocks = M / 256;
        if (lvl == DEPTH - 1)
            level_kernel<true><<<blocks, 256, 0, stream>>>(
                feat, w_iou, b_iou, u_iou, w_f, b_f, u_f, h, c, lvl);
        else
            level_kernel<false><<<blocks, 256, 0, stream>>>(
                feat, w_iou, b_iou, u_iou, w_f, b_f, u_f, h, c, lvl);
    }
    pool_partial<<<(SEGS * NTREES * H) / 256, 256, 0, stream>>>(h, part);
    pool_final<<<(NTREES * H) / 256, 256, 0, stream>>>(part, x);
    mlp_kernel<<<NTREES, H, 0, stream>>>(x, l0w, l0b, l1w, l1b, ow, ob, out);
}

// Round 2
// 2687.842 us; speedup vs baseline: 1.7462x; 1.7462x over previous
//
#include <hip/hip_runtime.h>
#include <math.h>

#define NTREES 512
#define DEPTH  10
#define NPT    1023
#define NTOT   (NTREES * NPT)   // 523776
#define H      64

__device__ __forceinline__ float sigm(float x)  { return 1.0f / (1.0f + __expf(-x)); }
__device__ __forceinline__ float ftanh(float x) { return 1.0f - 2.0f / (__expf(2.0f * x) + 1.0f); }

// Leaves (level 9): c = i*u, h = o*tanh(c); only w_iou needed.
// Outputs written feature-major: hT[j][node], cT[j][node] -> coalesced.
__global__ __launch_bounds__(256)
void leaf_kernel(const float* __restrict__ feat,
                 const float* __restrict__ w_iou,
                 const float* __restrict__ b_iou,
                 float* __restrict__ hT, float* __restrict__ cT)
{
    int tid  = blockIdx.x * 256 + threadIdx.x;   // 0..262143
    int tree = tid >> 9;
    int i    = tid & 511;
    int node = tree * NPT + 511 + i;

    float ft[H];
    const float4* p = reinterpret_cast<const float4*>(feat + (size_t)node * H);
    #pragma unroll
    for (int q = 0; q < H / 4; ++q) {
        float4 v = p[q];
        ft[4*q+0] = v.x; ft[4*q+1] = v.y; ft[4*q+2] = v.z; ft[4*q+3] = v.w;
    }

    for (int j = 0; j < H; ++j) {                // wave-uniform -> weights via s_load
        const float* wi = w_iou + j * H;
        const float* wo = w_iou + (H + j) * H;
        const float* wu = w_iou + (2 * H + j) * H;
        float ai = b_iou[j], ao = b_iou[H + j], au = b_iou[2 * H + j];
        #pragma unroll
        for (int k = 0; k < H; ++k) {
            float f = ft[k];
            ai = fmaf(wi[k], f, ai);
            ao = fmaf(wo[k], f, ao);
            au = fmaf(wu[k], f, au);
        }
        float cval = sigm(ai) * ftanh(au);
        cT[(size_t)j * NTOT + node] = cval;      // coalesced store
        hT[(size_t)j * NTOT + node] = sigm(ao) * ftanh(cval);
    }
}

// Internal levels (lvl = 8..0). lane = node; h/c feature-major.
// Children of consecutive lanes are interleaved -> all child reads coalesced.
__global__ __launch_bounds__(256, 2)
void internal_kernel(const float* __restrict__ feat,
                     const float* __restrict__ w_iou, const float* __restrict__ b_iou,
                     const float* __restrict__ u_iou,
                     const float* __restrict__ w_f, const float* __restrict__ b_f,
                     const float* __restrict__ u_f,
                     float* __restrict__ hT, float* __restrict__ cT,
                     int lvl)
{
    int tid   = blockIdx.x * 256 + threadIdx.x;
    int m     = 1 << lvl;
    int tree  = tid >> lvl;
    int i     = tid & (m - 1);
    int local = (m - 1) + i;
    int node  = tree * NPT + local;
    int cbase = tree * NPT + 2 * local + 1;      // lane stride 2 -> contiguous pair reads

    float ft[H];
    {
        const float4* p = reinterpret_cast<const float4*>(feat + (size_t)node * H);
        #pragma unroll
        for (int q = 0; q < H / 4; ++q) {
            float4 v = p[q];
            ft[4*q+0] = v.x; ft[4*q+1] = v.y; ft[4*q+2] = v.z; ft[4*q+3] = v.w;
        }
    }

    float h0[H], hs[H];                           // hs = h0 + h1
    #pragma unroll
    for (int k = 0; k < H; ++k) {
        const float* row = hT + (size_t)k * NTOT + cbase;
        float a = row[0];
        float b = row[1];
        h0[k] = a;
        hs[k] = a + b;
    }

    for (int j = 0; j < H; ++j) {                 // wave-uniform
        const float* wi = w_iou + j * H;
        const float* wo = w_iou + (H + j) * H;
        const float* wu = w_iou + (2 * H + j) * H;
        const float* ui = u_iou + j * H;
        const float* uo = u_iou + (H + j) * H;
        const float* uu = u_iou + (2 * H + j) * H;
        const float* wf = w_f + j * H;
        const float* uf = u_f + j * H;
        float ai = b_iou[j], ao = b_iou[H + j], au = b_iou[2 * H + j];
        float afx = b_f[j];
        float afs = 0.0f, af0 = 0.0f;
        #pragma unroll
        for (int k = 0; k < H; ++k) {
            float f = ft[k];
            float s = hs[k];
            float a = h0[k];
            ai  = fmaf(wi[k], f, ai);
            ao  = fmaf(wo[k], f, ao);
            au  = fmaf(wu[k], f, au);
            afx = fmaf(wf[k], f, afx);
            ai  = fmaf(ui[k], s, ai);
            ao  = fmaf(uo[k], s, ao);
            au  = fmaf(uu[k], s, au);
            afs = fmaf(uf[k], s, afs);
            af0 = fmaf(uf[k], a, af0);
        }
        float ig = sigm(ai), og = sigm(ao), ug = ftanh(au);
        float f0 = sigm(afx + af0);
        float f1 = sigm(afx + (afs - af0));
        const float* crow = cT + (size_t)j * NTOT + cbase;  // coalesced pair
        float cval = fmaf(ig, ug, f0 * crow[0] + f1 * crow[1]);
        cT[(size_t)j * NTOT + node] = cval;                 // coalesced store
        hT[(size_t)j * NTOT + node] = og * ftanh(cval);
    }
}

// One wave per (tree, j): sum 1023 contiguous floats of hT, relu(mean).
__global__ __launch_bounds__(256)
void pool_kernel(const float* __restrict__ hT, float* __restrict__ xp)
{
    int wv   = threadIdx.x >> 6;
    int lane = threadIdx.x & 63;
    int task = blockIdx.x * 4 + wv;              // 0..32767
    int tree = task >> 6;
    int j    = task & 63;
    const float* base = hT + (size_t)j * NTOT + tree * NPT;
    float s = 0.0f;
    #pragma unroll
    for (int t = 0; t < 16; ++t) {
        int i = t * 64 + lane;
        if (i < NPT) s += base[i];
    }
    #pragma unroll
    for (int off = 32; off > 0; off >>= 1) s += __shfl_down(s, off);
    if (lane == 0) xp[tree * H + j] = fmaxf(s * (1.0f / 1023.0f), 0.0f);
}

// One wave per tree: relu(lin0) -> relu(lin1) -> out dot.
__global__ void mlp_kernel(const float* __restrict__ x,
                           const float* __restrict__ l0w, const float* __restrict__ l0b,
                           const float* __restrict__ l1w, const float* __restrict__ l1b,
                           const float* __restrict__ ow,  const float* __restrict__ ob,
                           float* __restrict__ out)
{
    int tree = blockIdx.x;
    int j = threadIdx.x;
    __shared__ float xb[H];
    __shared__ float yb[H];
    xb[j] = x[tree * H + j];
    __syncthreads();
    float acc = l0b[j];
    #pragma unroll
    for (int k = 0; k < H; ++k) acc = fmaf(l0w[j * H + k], xb[k], acc);
    acc = fmaxf(acc, 0.0f);
    yb[j] = acc;
    __syncthreads();
    float acc2 = l1b[j];
    #pragma unroll
    for (int k = 0; k < H; ++k) acc2 = fmaf(l1w[j * H + k], yb[k], acc2);
    acc2 = fmaxf(acc2, 0.0f);
    float t = ow[j] * acc2;
    #pragma unroll
    for (int off = 32; off > 0; off >>= 1) t += __shfl_down(t, off);
    if (j == 0) out[tree] = t + ob[0];
}

extern "C" void kernel_launch(void* const* d_in, const int* in_sizes, int n_in,
                              void* d_out, int out_size, void* d_ws, size_t ws_size,
                              hipStream_t stream)
{
    const float* feat  = (const float*)d_in[0];
    // d_in[1..3]: node_order / adjacency / edge_order -- analytic heap structure, unused.
    const float* w_iou = (const float*)d_in[4];
    const float* b_iou = (const float*)d_in[5];
    const float* u_iou = (const float*)d_in[6];
    const float* w_f   = (const float*)d_in[7];
    const float* b_f   = (const float*)d_in[8];
    const float* u_f   = (const float*)d_in[9];
    const float* l0w   = (const float*)d_in[10];
    const float* l0b   = (const float*)d_in[11];
    const float* l1w   = (const float*)d_in[12];
    const float* l1b   = (const float*)d_in[13];
    const float* ow    = (const float*)d_in[14];
    const float* ob    = (const float*)d_in[15];
    float* out = (float*)d_out;

    // ws layout (fp32): hT[H][NTOT] | cT[H][NTOT] | xp[NTREES*H]   (~269 MB)
    float* hT = (float*)d_ws;
    float* cT = hT + (size_t)H * NTOT;
    float* xp = cT + (size_t)H * NTOT;

    leaf_kernel<<<(NTREES * 512) / 256, 256, 0, stream>>>(feat, w_iou, b_iou, hT, cT);
    for (int lvl = DEPTH - 2; lvl >= 0; --lvl) {
        int blocks = (NTREES << lvl) / 256;
        internal_kernel<<<blocks, 256, 0, stream>>>(
            feat, w_iou, b_iou, u_iou, w_f, b_f, u_f, hT, cT, lvl);
    }
    pool_kernel<<<(NTREES * H) / (256 / 64), 256, 0, stream>>>(hT, xp);
    mlp_kernel<<<NTREES, H, 0, stream>>>(xp, l0w, l0b, l1w, l1b, ow, ob, out);
}

// Round 3
// 577.044 us; speedup vs baseline: 8.1339x; 4.6579x over previous
//
#include <hip/hip_runtime.h>
#include <math.h>

#define NTREES 512
#define DEPTH  10
#define NPT    1023
#define NTOT   (NTREES * NPT)   // 523776
#define H      64

typedef __attribute__((ext_vector_type(8))) short bf16x8;
typedef __attribute__((ext_vector_type(4))) float f32x4;

__device__ __forceinline__ float sigm(float x)  { return 1.0f / (1.0f + __expf(-x)); }
__device__ __forceinline__ float ftanh(float x) { return 1.0f - 2.0f / (__expf(2.0f * x) + 1.0f); }

__device__ __forceinline__ unsigned short bf_hi(float f) {
    unsigned u = __float_as_uint(f);
    return (unsigned short)((u + 0x7fffu + ((u >> 16) & 1u)) >> 16);
}
__device__ __forceinline__ float bf_f(unsigned short h) {
    return __uint_as_float(((unsigned)h) << 16);
}
__device__ __forceinline__ void split8(const float v[8], bf16x8& hi, bf16x8& lo) {
    #pragma unroll
    for (int e = 0; e < 8; ++e) {
        unsigned short h = bf_hi(v[e]);
        hi[e] = (short)h;
        lo[e] = (short)bf_hi(v[e] - bf_f(h));
    }
}

// ---- B fragment prep: split weights into bf16 hi/lo in MFMA B-fragment layout.
// Frag-unit (8 ushort) offsets within B:
//   iou hi: frag (t*4+s)*64+l,  t=0..11, s=0..3   [0    .. 3072)
//   iou lo:                                        [3072 .. 6144)
//   fx  hi: 6144 + (t*2+s)*64+l, t=0..3, s=0..1
//   fx  lo: 6656 + ...
//   fu  hi: 7168 + ...   (serves both afs and af0)
//   fu  lo: 7680 + ...
// B element for (lane l, elem e, kstep s, tile t): col = t*16+(l&15), k = 32*s+8*(l>>4)+e.
__global__ void prep_b(const float* __restrict__ w_iou, const float* __restrict__ u_iou,
                       const float* __restrict__ w_f,  const float* __restrict__ u_f,
                       unsigned short* __restrict__ B)
{
    int idx = blockIdx.x * 256 + threadIdx.x;    // 0..32767
    float v;
    int hi_off, lo_off;
    if (idx < 24576) {                            // iou tiles: K=128 ([x|hs])
        int t   = idx >> 11;
        int rem = idx & 2047;
        int s   = rem >> 9;
        int l   = (rem >> 3) & 63;
        int e   = rem & 7;
        int col = t * 16 + (l & 15);
        int k   = 32 * s + 8 * (l >> 4) + e;
        v = (k < 64) ? w_iou[col * H + k] : u_iou[col * H + (k - 64)];
        hi_off = idx; lo_off = idx + 24576;
    } else if (idx < 28672) {                     // fx tiles: K=64 (x)
        int j = idx - 24576;
        int t = j >> 10; int rem = j & 1023;
        int s = rem >> 9; int l = (rem >> 3) & 63; int e = rem & 7;
        int col = t * 16 + (l & 15);
        int k   = 32 * s + 8 * (l >> 4) + e;
        v = w_f[col * H + k];
        hi_off = 49152 + j; lo_off = 53248 + j;
    } else {                                      // fu tiles: K=64 (hs or h0)
        int j = idx - 28672;
        int t = j >> 10; int rem = j & 1023;
        int s = rem >> 9; int l = (rem >> 3) & 63; int e = rem & 7;
        int col = t * 16 + (l & 15);
        int k   = 32 * s + 8 * (l >> 4) + e;
        v = u_f[col * H + k];
        hi_off = 57344 + j; lo_off = 61440 + j;
    }
    unsigned short hv = bf_hi(v);
    float lo = v - bf_f(hv);
    B[hi_off] = hv;
    B[lo_off] = bf_hi(lo);
}

#define MFMA(a, b, c) __builtin_amdgcn_mfma_f32_16x16x32_bf16((a), (b), (c), 0, 0, 0)

// ---- Leaves (heap level 9): c = i*u, h = o*tanh(c). One wave = 16 nodes, N=192.
__global__ __launch_bounds__(64)
void leaf_mfma(const float* __restrict__ feat, const unsigned short* __restrict__ Braw,
               const float* __restrict__ b_iou,
               float* __restrict__ h, float* __restrict__ c)
{
    int l = threadIdx.x;
    int base = blockIdx.x * 16;
    int g = base + (l & 15);
    int nrow = (g >> 9) * NPT + 511 + (g & 511);

    bf16x8 fh[2], fl[2];
    #pragma unroll
    for (int s = 0; s < 2; ++s) {
        float v[8];
        const float4* p = reinterpret_cast<const float4*>(feat + (size_t)nrow * H + 32 * s + 8 * (l >> 4));
        float4 a = p[0], b = p[1];
        v[0]=a.x; v[1]=a.y; v[2]=a.z; v[3]=a.w; v[4]=b.x; v[5]=b.y; v[6]=b.z; v[7]=b.w;
        split8(v, fh[s], fl[s]);
    }
    const bf16x8* Bp = reinterpret_cast<const bf16x8*>(Braw);
    f32x4 acc[12];
    #pragma unroll
    for (int t = 0; t < 12; ++t) acc[t] = (f32x4){0.f, 0.f, 0.f, 0.f};
    #pragma unroll
    for (int t = 0; t < 12; ++t) {
        #pragma unroll
        for (int s = 0; s < 2; ++s) {            // feat K-range only
            bf16x8 bh = Bp[(t * 4 + s) * 64 + l];
            bf16x8 bl = Bp[3072 + (t * 4 + s) * 64 + l];
            acc[t] = MFMA(fh[s], bh, acc[t]);
            acc[t] = MFMA(fh[s], bl, acc[t]);
            acc[t] = MFMA(fl[s], bh, acc[t]);
        }
    }
    int colb = l & 15;
    #pragma unroll
    for (int r = 0; r < 4; ++r) {
        int gr = base + (l >> 4) * 4 + r;
        int nr = (gr >> 9) * NPT + 511 + (gr & 511);
        #pragma unroll
        for (int t = 0; t < 4; ++t) {
            int j = 16 * t + colb;
            float ai = acc[t][r]     + b_iou[j];
            float ao = acc[4 + t][r] + b_iou[64 + j];
            float au = acc[8 + t][r] + b_iou[128 + j];
            float cv = sigm(ai) * ftanh(au);
            c[(size_t)nr * H + j] = cv;
            h[(size_t)nr * H + j] = sigm(ao) * ftanh(cv);
        }
    }
}

// ---- Internal levels (lvl 8..0). One wave = 16 nodes, N=384 (iou 192 | afx | afs | af0).
__global__ __launch_bounds__(64)
void internal_mfma(const float* __restrict__ feat, const unsigned short* __restrict__ Braw,
                   const float* __restrict__ b_iou, const float* __restrict__ b_f,
                   float* __restrict__ h, float* __restrict__ c, int lvl)
{
    int l = threadIdx.x;
    int m = 1 << lvl;
    int base = blockIdx.x * 16;
    int g = base + (l & 15);
    int tree = g >> lvl, i = g & (m - 1);
    int local = (m - 1) + i;
    int nrow  = tree * NPT + local;
    int crow0 = tree * NPT + 2 * local + 1;

    // A fragments: feat, hs = h0+h1, h0  (split on the fly)
    bf16x8 fh[2], fl[2], sh[2], sl[2], zh[2], zl[2];
    #pragma unroll
    for (int s = 0; s < 2; ++s) {
        int ko = 32 * s + 8 * (l >> 4);
        float v[8];
        {
            const float4* p = reinterpret_cast<const float4*>(feat + (size_t)nrow * H + ko);
            float4 a = p[0], b = p[1];
            v[0]=a.x; v[1]=a.y; v[2]=a.z; v[3]=a.w; v[4]=b.x; v[5]=b.y; v[6]=b.z; v[7]=b.w;
            split8(v, fh[s], fl[s]);
        }
        float v0[8], vs[8];
        {
            const float4* p0 = reinterpret_cast<const float4*>(h + (size_t)crow0 * H + ko);
            const float4* p1 = reinterpret_cast<const float4*>(h + (size_t)(crow0 + 1) * H + ko);
            float4 a0 = p0[0], b0 = p0[1], a1 = p1[0], b1 = p1[1];
            v0[0]=a0.x; v0[1]=a0.y; v0[2]=a0.z; v0[3]=a0.w; v0[4]=b0.x; v0[5]=b0.y; v0[6]=b0.z; v0[7]=b0.w;
            float w1[8];
            w1[0]=a1.x; w1[1]=a1.y; w1[2]=a1.z; w1[3]=a1.w; w1[4]=b1.x; w1[5]=b1.y; w1[6]=b1.z; w1[7]=b1.w;
            #pragma unroll
            for (int e = 0; e < 8; ++e) vs[e] = v0[e] + w1[e];
            split8(v0, zh[s], zl[s]);
            split8(vs, sh[s], sl[s]);
        }
    }

    const bf16x8* Bp = reinterpret_cast<const bf16x8*>(Braw);
    int colb = l & 15;

    // Phase 1: forget-gate accumulators (afx, afs, af0) -> f0,f1. fu frags reused.
    float f0[4][4], f1[4][4];
    #pragma unroll
    for (int t = 0; t < 4; ++t) {
        f32x4 ax = (f32x4){0.f,0.f,0.f,0.f};
        f32x4 as_ = ax, a0 = ax;
        #pragma unroll
        for (int s = 0; s < 2; ++s) {
            bf16x8 bxh = Bp[6144 + (t * 2 + s) * 64 + l];
            bf16x8 bxl = Bp[6656 + (t * 2 + s) * 64 + l];
            ax = MFMA(fh[s], bxh, ax); ax = MFMA(fh[s], bxl, ax); ax = MFMA(fl[s], bxh, ax);
            bf16x8 buh = Bp[7168 + (t * 2 + s) * 64 + l];
            bf16x8 bul = Bp[7680 + (t * 2 + s) * 64 + l];
            as_ = MFMA(sh[s], buh, as_); as_ = MFMA(sh[s], bul, as_); as_ = MFMA(sl[s], buh, as_);
            a0  = MFMA(zh[s], buh, a0);  a0  = MFMA(zh[s], bul, a0);  a0  = MFMA(zl[s], buh, a0);
        }
        #pragma unroll
        for (int r = 0; r < 4; ++r) {
            float afx = ax[r] + b_f[16 * t + colb];
            f0[t][r] = sigm(afx + a0[r]);
            f1[t][r] = sigm(afx + (as_[r] - a0[r]));
        }
    }

    // Phase 2: iou accumulators, K=128 over [x | hs].
    f32x4 acc[12];
    #pragma unroll
    for (int t = 0; t < 12; ++t) acc[t] = (f32x4){0.f,0.f,0.f,0.f};
    #pragma unroll
    for (int t = 0; t < 12; ++t) {
        #pragma unroll
        for (int s = 0; s < 4; ++s) {
            bf16x8 bh = Bp[(t * 4 + s) * 64 + l];
            bf16x8 bl = Bp[3072 + (t * 4 + s) * 64 + l];
            bf16x8 ah = (s < 2) ? fh[s] : sh[s - 2];
            bf16x8 al = (s < 2) ? fl[s] : sl[s - 2];
            acc[t] = MFMA(ah, bh, acc[t]);
            acc[t] = MFMA(ah, bl, acc[t]);
            acc[t] = MFMA(al, bh, acc[t]);
        }
    }

    // Epilogue: gates are lane-local; c-child reads coalesced per 16-lane group.
    #pragma unroll
    for (int r = 0; r < 4; ++r) {
        int gr = base + (l >> 4) * 4 + r;
        int treer = gr >> lvl, ir = gr & (m - 1);
        int lr = (m - 1) + ir;
        int nr = treer * NPT + lr;
        size_t ch0 = (size_t)(treer * NPT + 2 * lr + 1) * H;
        size_t ch1 = ch0 + H;
        #pragma unroll
        for (int t = 0; t < 4; ++t) {
            int j = 16 * t + colb;
            float ai = acc[t][r]     + b_iou[j];
            float ao = acc[4 + t][r] + b_iou[64 + j];
            float au = acc[8 + t][r] + b_iou[128 + j];
            float cv = sigm(ai) * ftanh(au) + f0[t][r] * c[ch0 + j] + f1[t][r] * c[ch1 + j];
            c[(size_t)nr * H + j] = cv;
            h[(size_t)nr * H + j] = sigm(ao) * ftanh(cv);
        }
    }
}

// ---- Mean-pool + relu: one block per tree.
__global__ __launch_bounds__(256)
void pool_kernel(const float* __restrict__ h, float* __restrict__ x)
{
    __shared__ float red[4][H];
    int tree = blockIdx.x;
    int f = threadIdx.x & 63;
    int seg = threadIdx.x >> 6;
    const float* basep = h + (size_t)tree * NPT * H;
    int i0 = seg * 256, i1 = i0 + 256; if (i1 > NPT) i1 = NPT;
    float s = 0.f;
    for (int i = i0; i < i1; ++i) s += basep[i * H + f];
    red[seg][f] = s;
    __syncthreads();
    if (seg == 0) {
        float tot = red[0][f] + red[1][f] + red[2][f] + red[3][f];
        x[tree * H + f] = fmaxf(tot * (1.0f / 1023.0f), 0.0f);
    }
}

// ---- MLP head: one wave per tree.
__global__ __launch_bounds__(64)
void mlp_kernel(const float* __restrict__ x,
                const float* __restrict__ l0w, const float* __restrict__ l0b,
                const float* __restrict__ l1w, const float* __restrict__ l1b,
                const float* __restrict__ ow,  const float* __restrict__ ob,
                float* __restrict__ out)
{
    int tree = blockIdx.x;
    int j = threadIdx.x;
    __shared__ float xb[H];
    __shared__ float yb[H];
    xb[j] = x[tree * H + j];
    __syncthreads();
    float acc = l0b[j];
    #pragma unroll
    for (int k = 0; k < H; ++k) acc = fmaf(l0w[j * H + k], xb[k], acc);
    acc = fmaxf(acc, 0.0f);
    yb[j] = acc;
    __syncthreads();
    float acc2 = l1b[j];
    #pragma unroll
    for (int k = 0; k < H; ++k) acc2 = fmaf(l1w[j * H + k], yb[k], acc2);
    acc2 = fmaxf(acc2, 0.0f);
    float t = ow[j] * acc2;
    #pragma unroll
    for (int off = 32; off > 0; off >>= 1) t += __shfl_down(t, off);
    if (j == 0) out[tree] = t + ob[0];
}

extern "C" void kernel_launch(void* const* d_in, const int* in_sizes, int n_in,
                              void* d_out, int out_size, void* d_ws, size_t ws_size,
                              hipStream_t stream)
{
    const float* feat  = (const float*)d_in[0];
    // d_in[1..3]: node_order / adjacency / edge_order -- analytic heap structure, unused.
    const float* w_iou = (const float*)d_in[4];
    const float* b_iou = (const float*)d_in[5];
    const float* u_iou = (const float*)d_in[6];
    const float* w_f   = (const float*)d_in[7];
    const float* b_f   = (const float*)d_in[8];
    const float* u_f   = (const float*)d_in[9];
    const float* l0w   = (const float*)d_in[10];
    const float* l0b   = (const float*)d_in[11];
    const float* l1w   = (const float*)d_in[12];
    const float* l1b   = (const float*)d_in[13];
    const float* ow    = (const float*)d_in[14];
    const float* ob    = (const float*)d_in[15];
    float* out = (float*)d_out;

    // ws: h[NTOT*H] f32 | c[NTOT*H] f32 | x[NTREES*H] f32 | B frags (65536 ushort)
    float* h = (float*)d_ws;
    float* c = h + (size_t)NTOT * H;
    float* x = c + (size_t)NTOT * H;
    unsigned short* Bf = (unsigned short*)(x + NTREES * H);

    prep_b<<<128, 256, 0, stream>>>(w_iou, u_iou, w_f, u_f, Bf);
    leaf_mfma<<<(NTREES * 512) / 16, 64, 0, stream>>>(feat, Bf, b_iou, h, c);
    for (int lvl = DEPTH - 2; lvl >= 0; --lvl)
        internal_mfma<<<32 << lvl, 64, 0, stream>>>(feat, Bf, b_iou, b_f, h, c, lvl);
    pool_kernel<<<NTREES, 256, 0, stream>>>(h, x);
    mlp_kernel<<<NTREES, 64, 0, stream>>>(x, l0w, l0b, l1w, l1b, ow, ob, out);
}

// Round 4
// 417.573 us; speedup vs baseline: 11.2403x; 1.3819x over previous
//
#include <hip/hip_runtime.h>
#include <math.h>

#define NTREES 512
#define DEPTH  10
#define NPT    1023
#define NTOT   (NTREES * NPT)   // 523776
#define H      64

typedef __attribute__((ext_vector_type(8))) short bf16x8;
typedef __attribute__((ext_vector_type(4))) float f32x4;

__device__ __forceinline__ float sigm(float x)  { return 1.0f / (1.0f + __expf(-x)); }
__device__ __forceinline__ float ftanh(float x) { return 1.0f - 2.0f / (__expf(2.0f * x) + 1.0f); }

__device__ __forceinline__ unsigned short bf_hi(float f) {
    unsigned u = __float_as_uint(f);
    return (unsigned short)((u + 0x7fffu + ((u >> 16) & 1u)) >> 16);
}
__device__ __forceinline__ float bf_f(unsigned short h) {
    return __uint_as_float(((unsigned)h) << 16);
}
__device__ __forceinline__ void split8(const float v[8], bf16x8& hi, bf16x8& lo) {
    #pragma unroll
    for (int e = 0; e < 8; ++e) {
        unsigned short hh = bf_hi(v[e]);
        hi[e] = (short)hh;
        lo[e] = (short)bf_hi(v[e] - bf_f(hh));
    }
}

#define MFMA(a, b, c) __builtin_amdgcn_mfma_f32_16x16x32_bf16((a), (b), (c), 0, 0, 0)

// ---- B prep: bf16 hi/lo fragments, arranged in three LDS-stageable chunks.
// Chunk layout (unit = one 16B frag per lane; global unit index):
//   iou-x  (sp=0): unit =          ((t*2+s')*2+hl)*64 + l        t<12, s'<2   [0,    3072)
//   iou-hs (sp=1): unit = 3072 +   ((t*2+s')*2+hl)*64 + l                     [3072, 6144)
//   forget       : unit = 6144 + (((t*2+s)*2+xu)*2+hl)*64 + l    t<4,  s<2    [6144, 8192)
// Element (lane l, e, kstep s, tile t): col = t*16+(l&15), k = 32*s + 8*(l>>4) + e.
__global__ void prep_b(const float* __restrict__ w_iou, const float* __restrict__ u_iou,
                       const float* __restrict__ w_f,  const float* __restrict__ u_f,
                       unsigned short* __restrict__ B)
{
    int idx  = blockIdx.x * 256 + threadIdx.x;   // 0..65535
    int unit = idx >> 3;
    int e    = idx & 7;
    int l    = unit & 63;
    float v;
    int hl;
    if (unit < 6144) {
        int sp = (unit >= 3072) ? 1 : 0;
        int r  = unit - sp * 3072;
        int q  = r >> 6;           // 0..47
        hl     = q & 1;
        int ts = q >> 1;
        int s_ = ts & 1;
        int t  = ts >> 1;
        int s  = sp * 2 + s_;
        int col = t * 16 + (l & 15);
        int k   = 32 * s + 8 * (l >> 4) + e;
        v = (k < 64) ? w_iou[col * H + k] : u_iou[col * H + (k - 64)];
    } else {
        int r  = unit - 6144;
        int q  = r >> 6;           // 0..31
        hl     = q & 1;
        int xu = (q >> 1) & 1;
        int ts = q >> 2;
        int s  = ts & 1;
        int t  = ts >> 1;
        int col = t * 16 + (l & 15);
        int k   = 32 * s + 8 * (l >> 4) + e;
        v = xu ? u_f[col * H + k] : w_f[col * H + k];
    }
    unsigned short hv = bf_hi(v);
    B[idx] = hl ? bf_hi(v - bf_f(hv)) : hv;
}

// ---- Leaves: 4 waves/block, 16 nodes/wave; iou-x chunk staged in LDS.
__global__ __launch_bounds__(256, 3)
void leaf_mfma(const float* __restrict__ feat, const unsigned short* __restrict__ Braw,
               const float* __restrict__ b_iou,
               float* __restrict__ h, float* __restrict__ c)
{
    __shared__ bf16x8 Bs[3072];                  // 48KB
    int tid = threadIdx.x;
    int l   = tid & 63;
    int w   = tid >> 6;
    int base = blockIdx.x * 64 + w * 16;
    int g    = base + (l & 15);
    int nrow = (g >> 9) * NPT + 511 + (g & 511);
    int ko   = 8 * (l >> 4);

    const float* fb = feat + (size_t)nrow * H + ko;
    float4 fr0 = *(const float4*)(fb);
    float4 fr1 = *(const float4*)(fb + 4);
    float4 fr2 = *(const float4*)(fb + 32);
    float4 fr3 = *(const float4*)(fb + 36);

    const bf16x8* Bg = (const bf16x8*)Braw;
    for (int u = tid; u < 3072; u += 256) Bs[u] = Bg[u];
    __syncthreads();

    bf16x8 fh[2], fl[2];
    { float v[8] = {fr0.x,fr0.y,fr0.z,fr0.w,fr1.x,fr1.y,fr1.z,fr1.w}; split8(v, fh[0], fl[0]); }
    { float v[8] = {fr2.x,fr2.y,fr2.z,fr2.w,fr3.x,fr3.y,fr3.z,fr3.w}; split8(v, fh[1], fl[1]); }

    f32x4 acc[12];
    #pragma unroll
    for (int t = 0; t < 12; ++t) acc[t] = (f32x4){0.f,0.f,0.f,0.f};
    #pragma unroll
    for (int t = 0; t < 12; ++t) {
        #pragma unroll
        for (int s = 0; s < 2; ++s) {
            bf16x8 bh = Bs[((t * 2 + s) * 2 + 0) * 64 + l];
            bf16x8 bl = Bs[((t * 2 + s) * 2 + 1) * 64 + l];
            acc[t] = MFMA(fh[s], bh, acc[t]);
            acc[t] = MFMA(fh[s], bl, acc[t]);
            acc[t] = MFMA(fl[s], bh, acc[t]);
        }
    }
    int colb = l & 15;
    #pragma unroll
    for (int r = 0; r < 4; ++r) {
        int gr = base + (l >> 4) * 4 + r;
        int nr = (gr >> 9) * NPT + 511 + (gr & 511);
        #pragma unroll
        for (int t = 0; t < 4; ++t) {
            int j = 16 * t + colb;
            float ai = acc[t][r]     + b_iou[j];
            float ao = acc[4 + t][r] + b_iou[64 + j];
            float au = acc[8 + t][r] + b_iou[128 + j];
            float cv = sigm(ai) * ftanh(au);
            c[(size_t)nr * H + j] = cv;
            h[(size_t)nr * H + j] = sigm(ao) * ftanh(cv);
        }
    }
}

// ---- Internal levels: 4 waves/block, 16 nodes/wave; B staged through 48KB LDS
// in 3 chunks (forget 32KB, iou-x 48KB, iou-hs 48KB).
__global__ __launch_bounds__(256, 3)
void internal_mfma(const float* __restrict__ feat, const unsigned short* __restrict__ Braw,
                   const float* __restrict__ b_iou, const float* __restrict__ b_f,
                   float* __restrict__ h, float* __restrict__ c, int lvl)
{
    __shared__ bf16x8 Bs[3072];                  // 48KB
    int tid = threadIdx.x;
    int l   = tid & 63;
    int w   = tid >> 6;
    int m   = 1 << lvl;
    int base  = blockIdx.x * 64 + w * 16;
    int g     = base + (l & 15);
    int tree  = g >> lvl, i = g & (m - 1);
    int local = (m - 1) + i;
    int nrow  = tree * NPT + local;
    int crow0 = tree * NPT + 2 * local + 1;
    int ko    = 8 * (l >> 4);
    int colb  = l & 15;

    // issue all A loads first; latency hides under staging + barrier
    const float* fb  = feat + (size_t)nrow * H + ko;
    float4 fr0 = *(const float4*)(fb);
    float4 fr1 = *(const float4*)(fb + 4);
    float4 fr2 = *(const float4*)(fb + 32);
    float4 fr3 = *(const float4*)(fb + 36);
    const float* h0b = h + (size_t)crow0 * H + ko;
    const float* h1b = h0b + H;
    float4 a00 = *(const float4*)(h0b);
    float4 a01 = *(const float4*)(h0b + 4);
    float4 a02 = *(const float4*)(h0b + 32);
    float4 a03 = *(const float4*)(h0b + 36);
    float4 a10 = *(const float4*)(h1b);
    float4 a11 = *(const float4*)(h1b + 4);
    float4 a12 = *(const float4*)(h1b + 32);
    float4 a13 = *(const float4*)(h1b + 36);

    const bf16x8* Bg = (const bf16x8*)Braw;
    for (int u = tid; u < 2048; u += 256) Bs[u] = Bg[6144 + u];   // forget chunk
    __syncthreads();

    bf16x8 fh[2], fl[2], sh[2], sl[2], zh[2], zl[2];
    { float v[8] = {fr0.x,fr0.y,fr0.z,fr0.w,fr1.x,fr1.y,fr1.z,fr1.w}; split8(v, fh[0], fl[0]); }
    { float v[8] = {fr2.x,fr2.y,fr2.z,fr2.w,fr3.x,fr3.y,fr3.z,fr3.w}; split8(v, fh[1], fl[1]); }
    {
        float v0[8] = {a00.x,a00.y,a00.z,a00.w,a01.x,a01.y,a01.z,a01.w};
        float v1[8] = {a10.x,a10.y,a10.z,a10.w,a11.x,a11.y,a11.z,a11.w};
        float vs[8];
        #pragma unroll
        for (int e = 0; e < 8; ++e) vs[e] = v0[e] + v1[e];
        split8(v0, zh[0], zl[0]); split8(vs, sh[0], sl[0]);
    }
    {
        float v0[8] = {a02.x,a02.y,a02.z,a02.w,a03.x,a03.y,a03.z,a03.w};
        float v1[8] = {a12.x,a12.y,a12.z,a12.w,a13.x,a13.y,a13.z,a13.w};
        float vs[8];
        #pragma unroll
        for (int e = 0; e < 8; ++e) vs[e] = v0[e] + v1[e];
        split8(v0, zh[1], zl[1]); split8(vs, sh[1], sl[1]);
    }

    // Phase F: forget gates (afx, af_sum, af_h0)
    float f0[4][4], f1[4][4];
    #pragma unroll
    for (int t = 0; t < 4; ++t) {
        f32x4 ax  = (f32x4){0.f,0.f,0.f,0.f};
        f32x4 as_ = (f32x4){0.f,0.f,0.f,0.f};
        f32x4 az  = (f32x4){0.f,0.f,0.f,0.f};
        #pragma unroll
        for (int s = 0; s < 2; ++s) {
            int qb = (t * 2 + s) * 4;
            bf16x8 bxh = Bs[(qb + 0) * 64 + l];
            bf16x8 bxl = Bs[(qb + 1) * 64 + l];
            bf16x8 buh = Bs[(qb + 2) * 64 + l];
            bf16x8 bul = Bs[(qb + 3) * 64 + l];
            ax  = MFMA(fh[s], bxh, ax);  ax  = MFMA(fh[s], bxl, ax);  ax  = MFMA(fl[s], bxh, ax);
            as_ = MFMA(sh[s], buh, as_); as_ = MFMA(sh[s], bul, as_); as_ = MFMA(sl[s], buh, as_);
            az  = MFMA(zh[s], buh, az);  az  = MFMA(zh[s], bul, az);  az  = MFMA(zl[s], buh, az);
        }
        #pragma unroll
        for (int r = 0; r < 4; ++r) {
            float afx = ax[r] + b_f[16 * t + colb];
            f0[t][r] = sigm(afx + az[r]);
            f1[t][r] = sigm(afx + (as_[r] - az[r]));
        }
    }
    __syncthreads();

    // Phase I.1: iou over x
    for (int u = tid; u < 3072; u += 256) Bs[u] = Bg[u];
    __syncthreads();
    f32x4 acc[12];
    #pragma unroll
    for (int t = 0; t < 12; ++t) acc[t] = (f32x4){0.f,0.f,0.f,0.f};
    #pragma unroll
    for (int t = 0; t < 12; ++t) {
        #pragma unroll
        for (int s = 0; s < 2; ++s) {
            bf16x8 bh = Bs[((t * 2 + s) * 2 + 0) * 64 + l];
            bf16x8 bl = Bs[((t * 2 + s) * 2 + 1) * 64 + l];
            acc[t] = MFMA(fh[s], bh, acc[t]);
            acc[t] = MFMA(fh[s], bl, acc[t]);
            acc[t] = MFMA(fl[s], bh, acc[t]);
        }
    }
    __syncthreads();

    // Phase I.2: iou over hs
    for (int u = tid; u < 3072; u += 256) Bs[u] = Bg[3072 + u];
    __syncthreads();
    #pragma unroll
    for (int t = 0; t < 12; ++t) {
        #pragma unroll
        for (int s = 0; s < 2; ++s) {
            bf16x8 bh = Bs[((t * 2 + s) * 2 + 0) * 64 + l];
            bf16x8 bl = Bs[((t * 2 + s) * 2 + 1) * 64 + l];
            acc[t] = MFMA(sh[s], bh, acc[t]);
            acc[t] = MFMA(sh[s], bl, acc[t]);
            acc[t] = MFMA(sl[s], bh, acc[t]);
        }
    }

    // Epilogue: lane-local gates; coalesced c-child reads per 16-lane group.
    #pragma unroll
    for (int r = 0; r < 4; ++r) {
        int gr = base + (l >> 4) * 4 + r;
        int treer = gr >> lvl, ir = gr & (m - 1);
        int lr = (m - 1) + ir;
        int nr = treer * NPT + lr;
        size_t ch0 = (size_t)(treer * NPT + 2 * lr + 1) * H;
        size_t ch1 = ch0 + H;
        #pragma unroll
        for (int t = 0; t < 4; ++t) {
            int j = 16 * t + colb;
            float ai = acc[t][r]     + b_iou[j];
            float ao = acc[4 + t][r] + b_iou[64 + j];
            float au = acc[8 + t][r] + b_iou[128 + j];
            float cv = sigm(ai) * ftanh(au) + f0[t][r] * c[ch0 + j] + f1[t][r] * c[ch1 + j];
            c[(size_t)nr * H + j] = cv;
            h[(size_t)nr * H + j] = sigm(ao) * ftanh(cv);
        }
    }
}

// ---- Mean-pool + relu: one block per tree.
__global__ __launch_bounds__(256)
void pool_kernel(const float* __restrict__ h, float* __restrict__ x)
{
    __shared__ float red[4][H];
    int tree = blockIdx.x;
    int f = threadIdx.x & 63;
    int seg = threadIdx.x >> 6;
    const float* basep = h + (size_t)tree * NPT * H;
    int i0 = seg * 256, i1 = i0 + 256; if (i1 > NPT) i1 = NPT;
    float s = 0.f;
    for (int i = i0; i < i1; ++i) s += basep[i * H + f];
    red[seg][f] = s;
    __syncthreads();
    if (seg == 0) {
        float tot = red[0][f] + red[1][f] + red[2][f] + red[3][f];
        x[tree * H + f] = fmaxf(tot * (1.0f / 1023.0f), 0.0f);
    }
}

// ---- MLP head: one wave per tree.
__global__ __launch_bounds__(64)
void mlp_kernel(const float* __restrict__ x,
                const float* __restrict__ l0w, const float* __restrict__ l0b,
                const float* __restrict__ l1w, const float* __restrict__ l1b,
                const float* __restrict__ ow,  const float* __restrict__ ob,
                float* __restrict__ out)
{
    int tree = blockIdx.x;
    int j = threadIdx.x;
    __shared__ float xb[H];
    __shared__ float yb[H];
    xb[j] = x[tree * H + j];
    __syncthreads();
    float acc = l0b[j];
    #pragma unroll
    for (int k = 0; k < H; ++k) acc = fmaf(l0w[j * H + k], xb[k], acc);
    acc = fmaxf(acc, 0.0f);
    yb[j] = acc;
    __syncthreads();
    float acc2 = l1b[j];
    #pragma unroll
    for (int k = 0; k < H; ++k) acc2 = fmaf(l1w[j * H + k], yb[k], acc2);
    acc2 = fmaxf(acc2, 0.0f);
    float t = ow[j] * acc2;
    #pragma unroll
    for (int off = 32; off > 0; off >>= 1) t += __shfl_down(t, off);
    if (j == 0) out[tree] = t + ob[0];
}

extern "C" void kernel_launch(void* const* d_in, const int* in_sizes, int n_in,
                              void* d_out, int out_size, void* d_ws, size_t ws_size,
                              hipStream_t stream)
{
    const float* feat  = (const float*)d_in[0];
    // d_in[1..3]: node_order / adjacency / edge_order -- analytic heap structure, unused.
    const float* w_iou = (const float*)d_in[4];
    const float* b_iou = (const float*)d_in[5];
    const float* u_iou = (const float*)d_in[6];
    const float* w_f   = (const float*)d_in[7];
    const float* b_f   = (const float*)d_in[8];
    const float* u_f   = (const float*)d_in[9];
    const float* l0w   = (const float*)d_in[10];
    const float* l0b   = (const float*)d_in[11];
    const float* l1w   = (const float*)d_in[12];
    const float* l1b   = (const float*)d_in[13];
    const float* ow    = (const float*)d_in[14];
    const float* ob    = (const float*)d_in[15];
    float* out = (float*)d_out;

    // ws: h[NTOT*H] f32 | c[NTOT*H] f32 | x[NTREES*H] f32 | B frags (65536 ushort)
    float* h = (float*)d_ws;
    float* c = h + (size_t)NTOT * H;
    float* x = c + (size_t)NTOT * H;
    unsigned short* Bf = (unsigned short*)(x + NTREES * H);

    prep_b<<<256, 256, 0, stream>>>(w_iou, u_iou, w_f, u_f, Bf);
    leaf_mfma<<<4096, 256, 0, stream>>>(feat, Bf, b_iou, h, c);
    for (int lvl = DEPTH - 2; lvl >= 0; --lvl)
        internal_mfma<<<8 << lvl, 256, 0, stream>>>(feat, Bf, b_iou, b_f, h, c, lvl);
    pool_kernel<<<NTREES, 256, 0, stream>>>(h, x);
    mlp_kernel<<<NTREES, 64, 0, stream>>>(x, l0w, l0b, l1w, l1b, ow, ob, out);
}

// Round 5
// 336.399 us; speedup vs baseline: 13.9525x; 1.2413x over previous
//
#include <hip/hip_runtime.h>
#include <math.h>

#define NTREES 512
#define DEPTH  10
#define NPT    1023
#define NTOT   (NTREES * NPT)   // 523776
#define H      64
#define PART_SLOTS 32256        // wave partials for levels 9(leaf)..4

typedef __attribute__((ext_vector_type(8))) short bf16x8;
typedef __attribute__((ext_vector_type(4))) float f32x4;

__device__ __forceinline__ float sigm(float x)  { return 1.0f / (1.0f + __expf(-x)); }
__device__ __forceinline__ float ftanh(float x) { return 1.0f - 2.0f / (__expf(2.0f * x) + 1.0f); }

__device__ __forceinline__ unsigned short bf_hi(float f) {
    unsigned u = __float_as_uint(f);
    return (unsigned short)((u + 0x7fffu + ((u >> 16) & 1u)) >> 16);
}
__device__ __forceinline__ float bf_f(unsigned short h) {
    return __uint_as_float(((unsigned)h) << 16);
}
__device__ __forceinline__ void split8(const float v[8], bf16x8& hi, bf16x8& lo) {
    #pragma unroll
    for (int e = 0; e < 8; ++e) {
        unsigned short hh = bf_hi(v[e]);
        hi[e] = (short)hh;
        lo[e] = (short)bf_hi(v[e] - bf_f(hh));
    }
}

#define MFMA(a, b, c) __builtin_amdgcn_mfma_f32_16x16x32_bf16((a), (b), (c), 0, 0, 0)

// ---- B prep (unchanged from round 3) ----
__global__ void prep_b(const float* __restrict__ w_iou, const float* __restrict__ u_iou,
                       const float* __restrict__ w_f,  const float* __restrict__ u_f,
                       unsigned short* __restrict__ B)
{
    int idx  = blockIdx.x * 256 + threadIdx.x;   // 0..65535
    int unit = idx >> 3;
    int e    = idx & 7;
    int l    = unit & 63;
    float v;
    int hl;
    if (unit < 6144) {
        int sp = (unit >= 3072) ? 1 : 0;
        int r  = unit - sp * 3072;
        int q  = r >> 6;
        hl     = q & 1;
        int ts = q >> 1;
        int s_ = ts & 1;
        int t  = ts >> 1;
        int s  = sp * 2 + s_;
        int col = t * 16 + (l & 15);
        int k   = 32 * s + 8 * (l >> 4) + e;
        v = (k < 64) ? w_iou[col * H + k] : u_iou[col * H + (k - 64)];
    } else {
        int r  = unit - 6144;
        int q  = r >> 6;
        hl     = q & 1;
        int xu = (q >> 1) & 1;
        int ts = q >> 2;
        int s  = ts & 1;
        int t  = ts >> 1;
        int col = t * 16 + (l & 15);
        int k   = 32 * s + 8 * (l >> 4) + e;
        v = xu ? u_f[col * H + k] : w_f[col * H + k];
    }
    unsigned short hv = bf_hi(v);
    B[idx] = hl ? bf_hi(v - bf_f(hv)) : hv;
}

// Per-wave pooling partial: lane holds hval for 4 rows (r) x 4 cols (t).
// psum[t] = per-lane row-sum; butterfly over the four 16-lane groups; store 64 floats.
__device__ __forceinline__ void store_partial(float psum[4], int l, int wid,
                                              float* __restrict__ partw)
{
    #pragma unroll
    for (int t = 0; t < 4; ++t) {
        float v = psum[t];
        v += __shfl_xor(v, 16);
        v += __shfl_xor(v, 32);
        if (l < 16) partw[(size_t)wid * H + 16 * t + l] = v;
    }
}

// ---- Leaves: 4 waves/block, 16 nodes/wave; iou-x chunk staged in LDS.
__global__ __launch_bounds__(256, 3)
void leaf_mfma(const float* __restrict__ feat, const unsigned short* __restrict__ Braw,
               const float* __restrict__ b_iou,
               float* __restrict__ h, float* __restrict__ c,
               float* __restrict__ partw, int do_part)
{
    __shared__ bf16x8 Bs[3072];                  // 48KB
    int tid = threadIdx.x;
    int l   = tid & 63;
    int w   = tid >> 6;
    int base = blockIdx.x * 64 + w * 16;
    int g    = base + (l & 15);
    int nrow = (g >> 9) * NPT + 511 + (g & 511);
    int ko   = 8 * (l >> 4);

    const float* fb = feat + (size_t)nrow * H + ko;
    float4 fr0 = *(const float4*)(fb);
    float4 fr1 = *(const float4*)(fb + 4);
    float4 fr2 = *(const float4*)(fb + 32);
    float4 fr3 = *(const float4*)(fb + 36);

    const bf16x8* Bg = (const bf16x8*)Braw;
    for (int u = tid; u < 3072; u += 256) Bs[u] = Bg[u];
    __syncthreads();

    bf16x8 fh[2], fl[2];
    { float v[8] = {fr0.x,fr0.y,fr0.z,fr0.w,fr1.x,fr1.y,fr1.z,fr1.w}; split8(v, fh[0], fl[0]); }
    { float v[8] = {fr2.x,fr2.y,fr2.z,fr2.w,fr3.x,fr3.y,fr3.z,fr3.w}; split8(v, fh[1], fl[1]); }

    f32x4 acc[12];
    #pragma unroll
    for (int t = 0; t < 12; ++t) acc[t] = (f32x4){0.f,0.f,0.f,0.f};
    #pragma unroll
    for (int t = 0; t < 12; ++t) {
        #pragma unroll
        for (int s = 0; s < 2; ++s) {
            bf16x8 bh = Bs[((t * 2 + s) * 2 + 0) * 64 + l];
            bf16x8 bl = Bs[((t * 2 + s) * 2 + 1) * 64 + l];
            acc[t] = MFMA(fh[s], bh, acc[t]);
            acc[t] = MFMA(fh[s], bl, acc[t]);
            acc[t] = MFMA(fl[s], bh, acc[t]);
        }
    }
    int colb = l & 15;
    float psum[4] = {0.f, 0.f, 0.f, 0.f};
    #pragma unroll
    for (int r = 0; r < 4; ++r) {
        int gr = base + (l >> 4) * 4 + r;
        int nr = (gr >> 9) * NPT + 511 + (gr & 511);
        #pragma unroll
        for (int t = 0; t < 4; ++t) {
            int j = 16 * t + colb;
            float ai = acc[t][r]     + b_iou[j];
            float ao = acc[4 + t][r] + b_iou[64 + j];
            float au = acc[8 + t][r] + b_iou[128 + j];
            float cv = sigm(ai) * ftanh(au);
            float hv = sigm(ao) * ftanh(cv);
            c[(size_t)nr * H + j] = cv;
            h[(size_t)nr * H + j] = hv;
            psum[t] += hv;
        }
    }
    if (do_part) store_partial(psum, l, blockIdx.x * 4 + w, partw);
}

// ---- Internal levels: 4 waves/block, 16 nodes/wave; B staged through 48KB LDS.
// woff >= 0: store per-wave pooling partial at slot woff + blockIdx*4 + w.
__global__ __launch_bounds__(256, 3)
void internal_mfma(const float* __restrict__ feat, const unsigned short* __restrict__ Braw,
                   const float* __restrict__ b_iou, const float* __restrict__ b_f,
                   float* __restrict__ h, float* __restrict__ c, int lvl,
                   float* __restrict__ partw, int woff)
{
    __shared__ bf16x8 Bs[3072];                  // 48KB
    int tid = threadIdx.x;
    int l   = tid & 63;
    int w   = tid >> 6;
    int m   = 1 << lvl;
    int base  = blockIdx.x * 64 + w * 16;
    int g     = base + (l & 15);
    int tree  = g >> lvl, i = g & (m - 1);
    int local = (m - 1) + i;
    int nrow  = tree * NPT + local;
    int crow0 = tree * NPT + 2 * local + 1;
    int ko    = 8 * (l >> 4);
    int colb  = l & 15;

    // issue all A loads first; latency hides under staging + barrier
    const float* fb  = feat + (size_t)nrow * H + ko;
    float4 fr0 = *(const float4*)(fb);
    float4 fr1 = *(const float4*)(fb + 4);
    float4 fr2 = *(const float4*)(fb + 32);
    float4 fr3 = *(const float4*)(fb + 36);
    const float* h0b = h + (size_t)crow0 * H + ko;
    const float* h1b = h0b + H;
    float4 a00 = *(const float4*)(h0b);
    float4 a01 = *(const float4*)(h0b + 4);
    float4 a02 = *(const float4*)(h0b + 32);
    float4 a03 = *(const float4*)(h0b + 36);
    float4 a10 = *(const float4*)(h1b);
    float4 a11 = *(const float4*)(h1b + 4);
    float4 a12 = *(const float4*)(h1b + 32);
    float4 a13 = *(const float4*)(h1b + 36);

    const bf16x8* Bg = (const bf16x8*)Braw;
    for (int u = tid; u < 2048; u += 256) Bs[u] = Bg[6144 + u];   // forget chunk
    __syncthreads();

    bf16x8 fh[2], fl[2], sh[2], sl[2], zh[2], zl[2];
    { float v[8] = {fr0.x,fr0.y,fr0.z,fr0.w,fr1.x,fr1.y,fr1.z,fr1.w}; split8(v, fh[0], fl[0]); }
    { float v[8] = {fr2.x,fr2.y,fr2.z,fr2.w,fr3.x,fr3.y,fr3.z,fr3.w}; split8(v, fh[1], fl[1]); }
    {
        float v0[8] = {a00.x,a00.y,a00.z,a00.w,a01.x,a01.y,a01.z,a01.w};
        float v1[8] = {a10.x,a10.y,a10.z,a10.w,a11.x,a11.y,a11.z,a11.w};
        float vs[8];
        #pragma unroll
        for (int e = 0; e < 8; ++e) vs[e] = v0[e] + v1[e];
        split8(v0, zh[0], zl[0]); split8(vs, sh[0], sl[0]);
    }
    {
        float v0[8] = {a02.x,a02.y,a02.z,a02.w,a03.x,a03.y,a03.z,a03.w};
        float v1[8] = {a12.x,a12.y,a12.z,a12.w,a13.x,a13.y,a13.z,a13.w};
        float vs[8];
        #pragma unroll
        for (int e = 0; e < 8; ++e) vs[e] = v0[e] + v1[e];
        split8(v0, zh[1], zl[1]); split8(vs, sh[1], sl[1]);
    }

    // Phase F: forget gates (afx, af_sum, af_h0)
    float f0[4][4], f1[4][4];
    #pragma unroll
    for (int t = 0; t < 4; ++t) {
        f32x4 ax  = (f32x4){0.f,0.f,0.f,0.f};
        f32x4 as_ = (f32x4){0.f,0.f,0.f,0.f};
        f32x4 az  = (f32x4){0.f,0.f,0.f,0.f};
        #pragma unroll
        for (int s = 0; s < 2; ++s) {
            int qb = (t * 2 + s) * 4;
            bf16x8 bxh = Bs[(qb + 0) * 64 + l];
            bf16x8 bxl = Bs[(qb + 1) * 64 + l];
            bf16x8 buh = Bs[(qb + 2) * 64 + l];
            bf16x8 bul = Bs[(qb + 3) * 64 + l];
            ax  = MFMA(fh[s], bxh, ax);  ax  = MFMA(fh[s], bxl, ax);  ax  = MFMA(fl[s], bxh, ax);
            as_ = MFMA(sh[s], buh, as_); as_ = MFMA(sh[s], bul, as_); as_ = MFMA(sl[s], buh, as_);
            az  = MFMA(zh[s], buh, az);  az  = MFMA(zh[s], bul, az);  az  = MFMA(zl[s], buh, az);
        }
        #pragma unroll
        for (int r = 0; r < 4; ++r) {
            float afx = ax[r] + b_f[16 * t + colb];
            f0[t][r] = sigm(afx + az[r]);
            f1[t][r] = sigm(afx + (as_[r] - az[r]));
        }
    }
    __syncthreads();

    // Phase I.1: iou over x
    for (int u = tid; u < 3072; u += 256) Bs[u] = Bg[u];
    __syncthreads();
    f32x4 acc[12];
    #pragma unroll
    for (int t = 0; t < 12; ++t) acc[t] = (f32x4){0.f,0.f,0.f,0.f};
    #pragma unroll
    for (int t = 0; t < 12; ++t) {
        #pragma unroll
        for (int s = 0; s < 2; ++s) {
            bf16x8 bh = Bs[((t * 2 + s) * 2 + 0) * 64 + l];
            bf16x8 bl = Bs[((t * 2 + s) * 2 + 1) * 64 + l];
            acc[t] = MFMA(fh[s], bh, acc[t]);
            acc[t] = MFMA(fh[s], bl, acc[t]);
            acc[t] = MFMA(fl[s], bh, acc[t]);
        }
    }
    __syncthreads();

    // Phase I.2: iou over hs
    for (int u = tid; u < 3072; u += 256) Bs[u] = Bg[3072 + u];
    __syncthreads();
    #pragma unroll
    for (int t = 0; t < 12; ++t) {
        #pragma unroll
        for (int s = 0; s < 2; ++s) {
            bf16x8 bh = Bs[((t * 2 + s) * 2 + 0) * 64 + l];
            bf16x8 bl = Bs[((t * 2 + s) * 2 + 1) * 64 + l];
            acc[t] = MFMA(sh[s], bh, acc[t]);
            acc[t] = MFMA(sh[s], bl, acc[t]);
            acc[t] = MFMA(sl[s], bh, acc[t]);
        }
    }

    // Epilogue: lane-local gates; coalesced c-child reads per 16-lane group.
    float psum[4] = {0.f, 0.f, 0.f, 0.f};
    #pragma unroll
    for (int r = 0; r < 4; ++r) {
        int gr = base + (l >> 4) * 4 + r;
        int treer = gr >> lvl, ir = gr & (m - 1);
        int lr = (m - 1) + ir;
        int nr = treer * NPT + lr;
        size_t ch0 = (size_t)(treer * NPT + 2 * lr + 1) * H;
        size_t ch1 = ch0 + H;
        #pragma unroll
        for (int t = 0; t < 4; ++t) {
            int j = 16 * t + colb;
            float ai = acc[t][r]     + b_iou[j];
            float ao = acc[4 + t][r] + b_iou[64 + j];
            float au = acc[8 + t][r] + b_iou[128 + j];
            float cv = sigm(ai) * ftanh(au) + f0[t][r] * c[ch0 + j] + f1[t][r] * c[ch1 + j];
            float hv = sigm(ao) * ftanh(cv);
            c[(size_t)nr * H + j] = cv;
            h[(size_t)nr * H + j] = hv;
            psum[t] += hv;
        }
    }
    if (woff >= 0) store_partial(psum, l, woff + blockIdx.x * 4 + w, partw);
}

// ---- Final: gather wave partials (levels 9..4) + h rows 0..14 (levels 3..0),
// mean -> relu -> 2-layer MLP -> out dot. One block (64 threads) per tree.
__global__ __launch_bounds__(64)
void final_mlp(const float* __restrict__ h, const float* __restrict__ partw,
               const float* __restrict__ l0w, const float* __restrict__ l0b,
               const float* __restrict__ l1w, const float* __restrict__ l1b,
               const float* __restrict__ ow,  const float* __restrict__ ob,
               float* __restrict__ out)
{
    int tree = blockIdx.x;
    int f = threadIdx.x;
    float s = 0.0f;
    #pragma unroll 4
    for (int k = 0; k < 32; ++k) s += partw[(size_t)(tree * 32 + k) * H + f];          // leaf
    #pragma unroll 4
    for (int k = 0; k < 16; ++k) s += partw[(size_t)(16384 + tree * 16 + k) * H + f];  // lvl8
    #pragma unroll
    for (int k = 0; k < 8; ++k)  s += partw[(size_t)(24576 + tree * 8 + k) * H + f];   // lvl7
    #pragma unroll
    for (int k = 0; k < 4; ++k)  s += partw[(size_t)(28672 + tree * 4 + k) * H + f];   // lvl6
    #pragma unroll
    for (int k = 0; k < 2; ++k)  s += partw[(size_t)(30720 + tree * 2 + k) * H + f];   // lvl5
    s += partw[(size_t)(31744 + tree) * H + f];                                        // lvl4
    const float* hb = h + (size_t)tree * NPT * H;
    #pragma unroll
    for (int i = 0; i < 15; ++i) s += hb[i * H + f];                                   // lvl3..0
    float x = fmaxf(s * (1.0f / 1023.0f), 0.0f);

    __shared__ float xb[H];
    __shared__ float yb[H];
    xb[f] = x;
    __syncthreads();
    float acc = l0b[f];
    #pragma unroll
    for (int k = 0; k < H; ++k) acc = fmaf(l0w[f * H + k], xb[k], acc);
    acc = fmaxf(acc, 0.0f);
    yb[f] = acc;
    __syncthreads();
    float acc2 = l1b[f];
    #pragma unroll
    for (int k = 0; k < H; ++k) acc2 = fmaf(l1w[f * H + k], yb[k], acc2);
    acc2 = fmaxf(acc2, 0.0f);
    float t = ow[f] * acc2;
    #pragma unroll
    for (int off = 32; off > 0; off >>= 1) t += __shfl_down(t, off);
    if (f == 0) out[tree] = t + ob[0];
}

// ---- Fallback path (ws too small for partials): standalone pool + mlp ----
__global__ __launch_bounds__(256)
void pool_kernel(const float* __restrict__ h, float* __restrict__ x)
{
    __shared__ float red[4][H];
    int tree = blockIdx.x;
    int f = threadIdx.x & 63;
    int seg = threadIdx.x >> 6;
    const float* basep = h + (size_t)tree * NPT * H;
    int i0 = seg * 256, i1 = i0 + 256; if (i1 > NPT) i1 = NPT;
    float s = 0.f;
    for (int i = i0; i < i1; ++i) s += basep[i * H + f];
    red[seg][f] = s;
    __syncthreads();
    if (seg == 0) {
        float tot = red[0][f] + red[1][f] + red[2][f] + red[3][f];
        x[tree * H + f] = fmaxf(tot * (1.0f / 1023.0f), 0.0f);
    }
}

__global__ __launch_bounds__(64)
void mlp_kernel(const float* __restrict__ x,
                const float* __restrict__ l0w, const float* __restrict__ l0b,
                const float* __restrict__ l1w, const float* __restrict__ l1b,
                const float* __restrict__ ow,  const float* __restrict__ ob,
                float* __restrict__ out)
{
    int tree = blockIdx.x;
    int j = threadIdx.x;
    __shared__ float xb[H];
    __shared__ float yb[H];
    xb[j] = x[tree * H + j];
    __syncthreads();
    float acc = l0b[j];
    #pragma unroll
    for (int k = 0; k < H; ++k) acc = fmaf(l0w[j * H + k], xb[k], acc);
    acc = fmaxf(acc, 0.0f);
    yb[j] = acc;
    __syncthreads();
    float acc2 = l1b[j];
    #pragma unroll
    for (int k = 0; k < H; ++k) acc2 = fmaf(l1w[j * H + k], yb[k], acc2);
    acc2 = fmaxf(acc2, 0.0f);
    float t = ow[j] * acc2;
    #pragma unroll
    for (int off = 32; off > 0; off >>= 1) t += __shfl_down(t, off);
    if (j == 0) out[tree] = t + ob[0];
}

extern "C" void kernel_launch(void* const* d_in, const int* in_sizes, int n_in,
                              void* d_out, int out_size, void* d_ws, size_t ws_size,
                              hipStream_t stream)
{
    const float* feat  = (const float*)d_in[0];
    // d_in[1..3]: node_order / adjacency / edge_order -- analytic heap structure, unused.
    const float* w_iou = (const float*)d_in[4];
    const float* b_iou = (const float*)d_in[5];
    const float* u_iou = (const float*)d_in[6];
    const float* w_f   = (const float*)d_in[7];
    const float* b_f   = (const float*)d_in[8];
    const float* u_f   = (const float*)d_in[9];
    const float* l0w   = (const float*)d_in[10];
    const float* l0b   = (const float*)d_in[11];
    const float* l1w   = (const float*)d_in[12];
    const float* l1b   = (const float*)d_in[13];
    const float* ow    = (const float*)d_in[14];
    const float* ob    = (const float*)d_in[15];
    float* out = (float*)d_out;

    // ws: h | c | x | Bf(128KB) | partw(8.26MB)
    float* h = (float*)d_ws;
    float* c = h + (size_t)NTOT * H;
    float* x = c + (size_t)NTOT * H;
    unsigned short* Bf = (unsigned short*)(x + NTREES * H);
    float* partw = (float*)(Bf + 65536);
    size_t needed = (size_t)((char*)(partw + (size_t)PART_SLOTS * H) - (char*)d_ws);
    int use_part = (ws_size >= needed) ? 1 : 0;

    prep_b<<<256, 256, 0, stream>>>(w_iou, u_iou, w_f, u_f, Bf);
    leaf_mfma<<<4096, 256, 0, stream>>>(feat, Bf, b_iou, h, c, partw, use_part);
    for (int lvl = DEPTH - 2; lvl >= 0; --lvl) {
        // wave-partial slot base: levels 8..4 at 32768 - (64<<lvl); lvl<4 -> none
        int woff = (use_part && lvl >= 4) ? (32768 - (64 << lvl)) : -1;
        internal_mfma<<<8 << lvl, 256, 0, stream>>>(
            feat, Bf, b_iou, b_f, h, c, lvl, partw, woff);
    }
    if (use_part) {
        final_mlp<<<NTREES, 64, 0, stream>>>(h, partw, l0w, l0b, l1w, l1b, ow, ob, out);
    } else {
        pool_kernel<<<NTREES, 256, 0, stream>>>(h, x);
        mlp_kernel<<<NTREES, 64, 0, stream>>>(x, l0w, l0b, l1w, l1b, ow, ob, out);
    }
}